// Round 3
// baseline (798.848 us; speedup 1.0000x reference)
//
#include <hip/hip_runtime.h>

// Problem constants (fixed by the reference)
#define D_MODEL 512
#define RATIO 4
#define NROWS 65536                    // L / RATIO
#define MTILE 64                       // pooled rows per GEMM block
#define GEMM_BLOCKS (NROWS / MTILE)    // 1024
#define POOL_ROWS_PER_BLOCK 16         // 4 waves x 4 rows
#define POOL_BLOCKS (NROWS / POOL_ROWS_PER_BLOCK)  // 4096

typedef __attribute__((ext_vector_type(8))) short short8;   // 8 bf16 (4 VGPRs) MFMA A/B frag
typedef __attribute__((ext_vector_type(4))) float f32x4;    // MFMA C/D frag

__device__ __forceinline__ unsigned short f32_to_bf16_rne(float f) {
    union { float f; unsigned int u; } v; v.f = f;
    unsigned int r = (v.u + 0x7FFFu + ((v.u >> 16) & 1u)) >> 16;
    return (unsigned short)r;
}

// Pre-convert w (512x512 fp32, row-major [out,in] == B^T layout) to bf16 in d_ws.
__global__ void convert_w_kernel(const float* __restrict__ w,
                                 unsigned short* __restrict__ wb) {
    int i = (blockIdx.x * blockDim.x + threadIdx.x) * 4;
    float4 v = *reinterpret_cast<const float4*>(w + i);
    ushort4 o;
    o.x = f32_to_bf16_rne(v.x);
    o.y = f32_to_bf16_rne(v.y);
    o.z = f32_to_bf16_rne(v.z);
    o.w = f32_to_bf16_rne(v.w);
    *reinterpret_cast<ushort4*>(wb + i) = o;
}

// ---------------------------------------------------------------------------
// Kernel 1: streaming attention-pool. High occupancy (no LDS, low VGPR),
// one wave per pooled row iteration, 4 rows per wave. Writes pooled bf16
// [NROWS x D_MODEL] linearly to workspace.
// ---------------------------------------------------------------------------
__global__ __launch_bounds__(256)
void pool_kernel(const float* __restrict__ chunk,
                 const float* __restrict__ query,
                 unsigned short* __restrict__ pooled) {
    const int tid  = threadIdx.x;
    const int wv   = tid >> 6;
    const int lane = tid & 63;

    // Query: lane owns 8 contiguous columns (same 8 it reads from every row)
    float q[8];
    {
        const float4 q0 = *reinterpret_cast<const float4*>(query + lane * 8);
        const float4 q1 = *reinterpret_cast<const float4*>(query + lane * 8 + 4);
        q[0] = q0.x; q[1] = q0.y; q[2] = q0.z; q[3] = q0.w;
        q[4] = q1.x; q[5] = q1.y; q[6] = q1.z; q[7] = q1.w;
    }

    const float inv_sqrt_d = 0.04419417382415922f;  // 1/sqrt(512)
    const int row0 = blockIdx.x * POOL_ROWS_PER_BLOCK + wv * 4;

    for (int i = 0; i < 4; ++i) {
        const int m = row0 + i;
        const size_t base = (size_t)m * (RATIO * D_MODEL) + lane * 8;
        float x[RATIO][8];
        float p[RATIO];
        #pragma unroll
        for (int r = 0; r < RATIO; ++r) {
            const float4 a = *reinterpret_cast<const float4*>(chunk + base + r * D_MODEL);
            const float4 c = *reinterpret_cast<const float4*>(chunk + base + r * D_MODEL + 4);
            x[r][0] = a.x; x[r][1] = a.y; x[r][2] = a.z; x[r][3] = a.w;
            x[r][4] = c.x; x[r][5] = c.y; x[r][6] = c.z; x[r][7] = c.w;
            float s = 0.f;
            #pragma unroll
            for (int j = 0; j < 8; ++j) s = fmaf(q[j], x[r][j], s);
            p[r] = s;
        }
        // 64-lane butterfly reduction of the 4 dot products
        #pragma unroll
        for (int off = 32; off; off >>= 1) {
            #pragma unroll
            for (int r = 0; r < RATIO; ++r) p[r] += __shfl_xor(p[r], off);
        }
        // softmax over 4 scores (fp32, every lane redundantly)
        const float s0 = p[0] * inv_sqrt_d, s1 = p[1] * inv_sqrt_d,
                    s2 = p[2] * inv_sqrt_d, s3 = p[3] * inv_sqrt_d;
        const float mx = fmaxf(fmaxf(s0, s1), fmaxf(s2, s3));
        const float e0 = __expf(s0 - mx), e1 = __expf(s1 - mx),
                    e2 = __expf(s2 - mx), e3 = __expf(s3 - mx);
        const float inv = 1.0f / (e0 + e1 + e2 + e3);
        const float a0 = e0 * inv, a1 = e1 * inv, a2 = e2 * inv, a3 = e3 * inv;

        short8 pv;
        #pragma unroll
        for (int j = 0; j < 8; ++j) {
            const float pj = a0 * x[0][j] + a1 * x[1][j] + a2 * x[2][j] + a3 * x[3][j];
            pv[j] = (short)f32_to_bf16_rne(pj);
        }
        *reinterpret_cast<short8*>(pooled + (size_t)m * D_MODEL + lane * 8) = pv;
    }
}

// ---------------------------------------------------------------------------
// Kernel 2: out[64 x 512] = pooled @ w^T + b per block, mfma_f32_16x16x32_bf16.
// Identical to the verified fused Stage 2; A-tile now loaded from global
// (swizzled on the LDS-write side: 16B-chunk kc of row m at kc ^ (m & 7)).
// ---------------------------------------------------------------------------
__global__ __launch_bounds__(256, 2)
void gemm_kernel(const unsigned short* __restrict__ pooled,
                 const unsigned short* __restrict__ wb,
                 const float* __restrict__ bias,
                 float* __restrict__ out) {
    __shared__ unsigned short a_lds[MTILE * D_MODEL];  // 64 KB

    const int tid  = threadIdx.x;
    const int wv   = tid >> 6;       // wave 0..3
    const int lane = tid & 63;
    const int m0   = blockIdx.x * MTILE;

    // A-tile load: wave wv stages local rows [wv*16, wv*16+16), swizzled.
    #pragma unroll 4
    for (int ri = 0; ri < 16; ++ri) {
        const int ml = wv * 16 + ri;
        const int kcs = lane ^ (ml & 7);
        *reinterpret_cast<short8*>(&a_lds[ml * D_MODEL + kcs * 8]) =
            *reinterpret_cast<const short8*>(pooled + (size_t)(m0 + ml) * D_MODEL + lane * 8);
    }
    __syncthreads();

    f32x4 acc[4][8];
    #pragma unroll
    for (int mt = 0; mt < 4; ++mt)
        #pragma unroll
        for (int nt = 0; nt < 8; ++nt)
            acc[mt][nt] = (f32x4){0.f, 0.f, 0.f, 0.f};

    const int lrow = lane & 15;   // A: m-offset in tile; B: n-offset; D: col
    const int quad = lane >> 4;
    const int n_base = wv * 128;

    for (int k0 = 0; k0 < D_MODEL; k0 += 32) {
        const int kq = (k0 >> 3) + quad;  // 16B-chunk index (pre-swizzle)
        short8 afrag[4];
        #pragma unroll
        for (int mt = 0; mt < 4; ++mt) {
            const int ml = mt * 16 + lrow;
            const int kc = kq ^ (ml & 7);
            afrag[mt] = *reinterpret_cast<const short8*>(&a_lds[ml * D_MODEL + kc * 8]);
        }
        short8 bfrag[8];
        #pragma unroll
        for (int nt = 0; nt < 8; ++nt) {
            const int n = n_base + nt * 16 + lrow;
            bfrag[nt] = *reinterpret_cast<const short8*>(
                wb + (size_t)n * D_MODEL + k0 + quad * 8);
        }
        #pragma unroll
        for (int mt = 0; mt < 4; ++mt)
            #pragma unroll
            for (int nt = 0; nt < 8; ++nt)
                acc[mt][nt] = __builtin_amdgcn_mfma_f32_16x16x32_bf16(
                    afrag[mt], bfrag[nt], acc[mt][nt], 0, 0, 0);
    }

    // Epilogue: C/D layout col = lane&15, row = quad*4 + reg.
    #pragma unroll
    for (int nt = 0; nt < 8; ++nt) {
        const int col = n_base + nt * 16 + lrow;
        const float bv = bias[col];
        #pragma unroll
        for (int mt = 0; mt < 4; ++mt) {
            float* op = out + (size_t)(m0 + mt * 16 + quad * 4) * D_MODEL + col;
            #pragma unroll
            for (int r = 0; r < 4; ++r)
                op[(size_t)r * D_MODEL] = acc[mt][nt][r] + bv;
        }
    }
}

// ---------------------------------------------------------------------------
// Fallback: verified fused kernel (used only if workspace is too small).
// ---------------------------------------------------------------------------
template <bool BF16W>
__global__ __launch_bounds__(256, 2)
void attn_pool_gemm_kernel(const float* __restrict__ chunk,
                           const float* __restrict__ query,
                           const float* __restrict__ w,
                           const unsigned short* __restrict__ wb,
                           const float* __restrict__ bias,
                           float* __restrict__ out) {
    __shared__ unsigned short a_lds[MTILE * D_MODEL];

    const int tid  = threadIdx.x;
    const int wv   = tid >> 6;
    const int lane = tid & 63;
    const int m0   = blockIdx.x * MTILE;

    float q[8];
    {
        const float4 q0 = *reinterpret_cast<const float4*>(query + lane * 8);
        const float4 q1 = *reinterpret_cast<const float4*>(query + lane * 8 + 4);
        q[0] = q0.x; q[1] = q0.y; q[2] = q0.z; q[3] = q0.w;
        q[4] = q1.x; q[5] = q1.y; q[6] = q1.z; q[7] = q1.w;
    }

    const float inv_sqrt_d = 0.04419417382415922f;

    for (int ri = 0; ri < 16; ++ri) {
        const int m_local = wv * 16 + ri;
        const size_t base = (size_t)(m0 + m_local) * (RATIO * D_MODEL) + lane * 8;
        float x[RATIO][8];
        float p[RATIO];
        #pragma unroll
        for (int r = 0; r < RATIO; ++r) {
            const float4 a = *reinterpret_cast<const float4*>(chunk + base + r * D_MODEL);
            const float4 c = *reinterpret_cast<const float4*>(chunk + base + r * D_MODEL + 4);
            x[r][0] = a.x; x[r][1] = a.y; x[r][2] = a.z; x[r][3] = a.w;
            x[r][4] = c.x; x[r][5] = c.y; x[r][6] = c.z; x[r][7] = c.w;
            float s = 0.f;
            #pragma unroll
            for (int j = 0; j < 8; ++j) s = fmaf(q[j], x[r][j], s);
            p[r] = s;
        }
        #pragma unroll
        for (int off = 32; off; off >>= 1) {
            #pragma unroll
            for (int r = 0; r < RATIO; ++r) p[r] += __shfl_xor(p[r], off);
        }
        const float s0 = p[0] * inv_sqrt_d, s1 = p[1] * inv_sqrt_d,
                    s2 = p[2] * inv_sqrt_d, s3 = p[3] * inv_sqrt_d;
        const float mx = fmaxf(fmaxf(s0, s1), fmaxf(s2, s3));
        const float e0 = __expf(s0 - mx), e1 = __expf(s1 - mx),
                    e2 = __expf(s2 - mx), e3 = __expf(s3 - mx);
        const float inv = 1.0f / (e0 + e1 + e2 + e3);
        const float a0 = e0 * inv, a1 = e1 * inv, a2 = e2 * inv, a3 = e3 * inv;

        short8 pv;
        #pragma unroll
        for (int j = 0; j < 8; ++j) {
            const float pj = a0 * x[0][j] + a1 * x[1][j] + a2 * x[2][j] + a3 * x[3][j];
            pv[j] = (short)f32_to_bf16_rne(pj);
        }
        const int kcs = lane ^ (m_local & 7);
        *reinterpret_cast<short8*>(&a_lds[m_local * D_MODEL + kcs * 8]) = pv;
    }
    __syncthreads();

    f32x4 acc[4][8];
    #pragma unroll
    for (int mt = 0; mt < 4; ++mt)
        #pragma unroll
        for (int nt = 0; nt < 8; ++nt)
            acc[mt][nt] = (f32x4){0.f, 0.f, 0.f, 0.f};

    const int lrow = lane & 15;
    const int quad = lane >> 4;
    const int n_base = wv * 128;

    for (int k0 = 0; k0 < D_MODEL; k0 += 32) {
        const int kq = (k0 >> 3) + quad;
        short8 afrag[4];
        #pragma unroll
        for (int mt = 0; mt < 4; ++mt) {
            const int ml = mt * 16 + lrow;
            const int kc = kq ^ (ml & 7);
            afrag[mt] = *reinterpret_cast<const short8*>(&a_lds[ml * D_MODEL + kc * 8]);
        }
        short8 bfrag[8];
        #pragma unroll
        for (int nt = 0; nt < 8; ++nt) {
            const int n = n_base + nt * 16 + lrow;
            if (BF16W) {
                bfrag[nt] = *reinterpret_cast<const short8*>(
                    wb + (size_t)n * D_MODEL + k0 + quad * 8);
            } else {
                const float4 c0 = *reinterpret_cast<const float4*>(
                    w + (size_t)n * D_MODEL + k0 + quad * 8);
                const float4 c1 = *reinterpret_cast<const float4*>(
                    w + (size_t)n * D_MODEL + k0 + quad * 8 + 4);
                bfrag[nt][0] = (short)f32_to_bf16_rne(c0.x);
                bfrag[nt][1] = (short)f32_to_bf16_rne(c0.y);
                bfrag[nt][2] = (short)f32_to_bf16_rne(c0.z);
                bfrag[nt][3] = (short)f32_to_bf16_rne(c0.w);
                bfrag[nt][4] = (short)f32_to_bf16_rne(c1.x);
                bfrag[nt][5] = (short)f32_to_bf16_rne(c1.y);
                bfrag[nt][6] = (short)f32_to_bf16_rne(c1.z);
                bfrag[nt][7] = (short)f32_to_bf16_rne(c1.w);
            }
        }
        #pragma unroll
        for (int mt = 0; mt < 4; ++mt)
            #pragma unroll
            for (int nt = 0; nt < 8; ++nt)
                acc[mt][nt] = __builtin_amdgcn_mfma_f32_16x16x32_bf16(
                    afrag[mt], bfrag[nt], acc[mt][nt], 0, 0, 0);
    }

    #pragma unroll
    for (int nt = 0; nt < 8; ++nt) {
        const int col = n_base + nt * 16 + lrow;
        const float bv = bias[col];
        #pragma unroll
        for (int mt = 0; mt < 4; ++mt) {
            float* op = out + (size_t)(m0 + mt * 16 + quad * 4) * D_MODEL + col;
            #pragma unroll
            for (int r = 0; r < 4; ++r)
                op[(size_t)r * D_MODEL] = acc[mt][nt][r] + bv;
        }
    }
}

extern "C" void kernel_launch(void* const* d_in, const int* in_sizes, int n_in,
                              void* d_out, int out_size, void* d_ws, size_t ws_size,
                              hipStream_t stream) {
    const float* chunk = (const float*)d_in[0];   // [262144, 512]
    const float* query = (const float*)d_in[1];   // [512]
    const float* w     = (const float*)d_in[2];   // [512, 512]
    const float* bias  = (const float*)d_in[3];   // [512]
    float* out = (float*)d_out;                   // [65536, 512]

    const size_t wb_bytes     = (size_t)D_MODEL * D_MODEL * sizeof(unsigned short); // 512 KB
    const size_t pooled_bytes = (size_t)NROWS * D_MODEL * sizeof(unsigned short);   // 64 MB

    if (ws_size >= wb_bytes + pooled_bytes && d_ws != nullptr) {
        // Split path: streaming pool (high occupancy) + MFMA GEMM.
        unsigned short* wb     = (unsigned short*)d_ws;
        unsigned short* pooled = (unsigned short*)((char*)d_ws + wb_bytes);
        convert_w_kernel<<<(D_MODEL * D_MODEL / 4) / 256, 256, 0, stream>>>(w, wb);
        pool_kernel<<<POOL_BLOCKS, 256, 0, stream>>>(chunk, query, pooled);
        gemm_kernel<<<GEMM_BLOCKS, 256, 0, stream>>>(pooled, wb, bias, out);
    } else if (ws_size >= wb_bytes && d_ws != nullptr) {
        unsigned short* wb = (unsigned short*)d_ws;
        convert_w_kernel<<<(D_MODEL * D_MODEL / 4) / 256, 256, 0, stream>>>(w, wb);
        attn_pool_gemm_kernel<true><<<GEMM_BLOCKS, 256, 0, stream>>>(
            chunk, query, w, wb, bias, out);
    } else {
        attn_pool_gemm_kernel<false><<<GEMM_BLOCKS, 256, 0, stream>>>(
            chunk, query, w, nullptr, bias, out);
    }
}

// Round 4
// 773.274 us; speedup vs baseline: 1.0331x; 1.0331x over previous
//
#include <hip/hip_runtime.h>
#include <hip/hip_bf16.h>

// Problem constants (fixed by the reference)
#define D_MODEL 512
#define RATIO 4
#define NROWS 65536              // L / RATIO
#define MTILE 64                 // pooled rows per block
#define GRID_BLOCKS (NROWS / MTILE)  // 1024

typedef __attribute__((ext_vector_type(8))) short short8;   // 8 bf16 (4 VGPRs) MFMA A/B frag
typedef __attribute__((ext_vector_type(4))) float f32x4;    // MFMA C/D frag

__device__ __forceinline__ unsigned short f32_to_bf16_rne(float f) {
    union { float f; unsigned int u; } v; v.f = f;
    unsigned int r = (v.u + 0x7FFFu + ((v.u >> 16) & 1u)) >> 16;
    return (unsigned short)r;
}

// Pre-convert w (512x512 fp32, row-major [out,in] == B^T layout) to bf16 in d_ws.
__global__ void convert_w_kernel(const float* __restrict__ w,
                                 unsigned short* __restrict__ wb) {
    int i = (blockIdx.x * blockDim.x + threadIdx.x) * 4;
    float4 v = *reinterpret_cast<const float4*>(w + i);
    ushort4 o;
    o.x = f32_to_bf16_rne(v.x);
    o.y = f32_to_bf16_rne(v.y);
    o.z = f32_to_bf16_rne(v.z);
    o.w = f32_to_bf16_rne(v.w);
    *reinterpret_cast<ushort4*>(wb + i) = o;
}

// Fused: attention-pool 64 rows into a 64x512 bf16 LDS tile (A operand),
// then GEMM vs w^T with mfma_f32_16x16x32_bf16. One block = 64 output rows,
// 4 waves each own a 128-col slice of N=512.
//
// Measured model (round 3): dur_us includes ~663 us of harness 2-GiB ws-poison
// fills; this kernel's controllable portion is ~110 us vs a 640 MB traffic
// floor of ~102 us — stage 1 is HBM-BW-bound at 8 waves/CU (demand ~40 B/cy/CU
// vs ~10 supply), so occupancy is NOT the limiter. Keep fused (minimum
// traffic: no pooled intermediate round-trip).
template <bool BF16W>
__global__ __launch_bounds__(256, 2)
void attn_pool_gemm_kernel(const float* __restrict__ chunk,
                           const float* __restrict__ query,
                           const float* __restrict__ w,
                           const unsigned short* __restrict__ wb,
                           const float* __restrict__ bias,
                           float* __restrict__ out) {
    // 64 KB exactly. XOR-swizzle at 16B-chunk granularity: element group kc of
    // row m stored at kc ^ (m & 7) -> conflict-free b128 reads/writes, no pad.
    __shared__ unsigned short a_lds[MTILE * D_MODEL];

    const int tid  = threadIdx.x;
    const int wv   = tid >> 6;       // wave 0..3
    const int lane = tid & 63;
    const int m0   = blockIdx.x * MTILE;

    // Query: lane owns 8 contiguous columns (same 8 it reads from every row)
    float q[8];
    {
        const float4 q0 = *reinterpret_cast<const float4*>(query + lane * 8);
        const float4 q1 = *reinterpret_cast<const float4*>(query + lane * 8 + 4);
        q[0] = q0.x; q[1] = q0.y; q[2] = q0.z; q[3] = q0.w;
        q[4] = q1.x; q[5] = q1.y; q[6] = q1.z; q[7] = q1.w;
    }

    const float inv_sqrt_d = 0.04419417382415922f;  // 1/sqrt(512)

    // ---- Stage 1: attention pooling. Wave wv handles local rows [wv*16, wv*16+16)
    for (int ri = 0; ri < 16; ++ri) {
        const int m_local = wv * 16 + ri;
        const size_t base = (size_t)(m0 + m_local) * (RATIO * D_MODEL) + lane * 8;
        float x[RATIO][8];
        float p[RATIO];
        #pragma unroll
        for (int r = 0; r < RATIO; ++r) {
            const float4 a = *reinterpret_cast<const float4*>(chunk + base + r * D_MODEL);
            const float4 c = *reinterpret_cast<const float4*>(chunk + base + r * D_MODEL + 4);
            x[r][0] = a.x; x[r][1] = a.y; x[r][2] = a.z; x[r][3] = a.w;
            x[r][4] = c.x; x[r][5] = c.y; x[r][6] = c.z; x[r][7] = c.w;
            float s = 0.f;
            #pragma unroll
            for (int j = 0; j < 8; ++j) s = fmaf(q[j], x[r][j], s);
            p[r] = s;
        }
        // 64-lane butterfly reduction of the 4 dot products
        #pragma unroll
        for (int off = 32; off; off >>= 1) {
            #pragma unroll
            for (int r = 0; r < RATIO; ++r) p[r] += __shfl_xor(p[r], off);
        }
        // softmax over 4 scores (fp32, every lane redundantly)
        const float s0 = p[0] * inv_sqrt_d, s1 = p[1] * inv_sqrt_d,
                    s2 = p[2] * inv_sqrt_d, s3 = p[3] * inv_sqrt_d;
        const float mx = fmaxf(fmaxf(s0, s1), fmaxf(s2, s3));
        const float e0 = __expf(s0 - mx), e1 = __expf(s1 - mx),
                    e2 = __expf(s2 - mx), e3 = __expf(s3 - mx);
        const float inv = 1.0f / (e0 + e1 + e2 + e3);
        const float a0 = e0 * inv, a1 = e1 * inv, a2 = e2 * inv, a3 = e3 * inv;

        short8 pv;
        #pragma unroll
        for (int j = 0; j < 8; ++j) {
            const float pj = a0 * x[0][j] + a1 * x[1][j] + a2 * x[2][j] + a3 * x[3][j];
            pv[j] = (short)f32_to_bf16_rne(pj);
        }
        const int kcs = lane ^ (m_local & 7);  // lane == 16B-chunk index
        *reinterpret_cast<short8*>(&a_lds[m_local * D_MODEL + kcs * 8]) = pv;
    }
    __syncthreads();

    // ---- Stage 2: out[64 x 512] = pooled @ w^T + b. Wave wv owns cols [wv*128, wv*128+128).
    f32x4 acc[4][8];
    #pragma unroll
    for (int mt = 0; mt < 4; ++mt)
        #pragma unroll
        for (int nt = 0; nt < 8; ++nt)
            acc[mt][nt] = (f32x4){0.f, 0.f, 0.f, 0.f};

    const int lrow = lane & 15;   // A: m-offset in tile; B: n-offset; D: col
    const int quad = lane >> 4;
    const int n_base = wv * 128;

    for (int k0 = 0; k0 < D_MODEL; k0 += 32) {
        const int kq = (k0 >> 3) + quad;  // 16B-chunk index (pre-swizzle)
        short8 afrag[4];
        #pragma unroll
        for (int mt = 0; mt < 4; ++mt) {
            const int ml = mt * 16 + lrow;
            const int kc = kq ^ (ml & 7);
            afrag[mt] = *reinterpret_cast<const short8*>(&a_lds[ml * D_MODEL + kc * 8]);
        }
        short8 bfrag[8];
        #pragma unroll
        for (int nt = 0; nt < 8; ++nt) {
            const int n = n_base + nt * 16 + lrow;
            if (BF16W) {
                bfrag[nt] = *reinterpret_cast<const short8*>(
                    wb + (size_t)n * D_MODEL + k0 + quad * 8);
            } else {
                const float4 c0 = *reinterpret_cast<const float4*>(
                    w + (size_t)n * D_MODEL + k0 + quad * 8);
                const float4 c1 = *reinterpret_cast<const float4*>(
                    w + (size_t)n * D_MODEL + k0 + quad * 8 + 4);
                bfrag[nt][0] = (short)f32_to_bf16_rne(c0.x);
                bfrag[nt][1] = (short)f32_to_bf16_rne(c0.y);
                bfrag[nt][2] = (short)f32_to_bf16_rne(c0.z);
                bfrag[nt][3] = (short)f32_to_bf16_rne(c0.w);
                bfrag[nt][4] = (short)f32_to_bf16_rne(c1.x);
                bfrag[nt][5] = (short)f32_to_bf16_rne(c1.y);
                bfrag[nt][6] = (short)f32_to_bf16_rne(c1.z);
                bfrag[nt][7] = (short)f32_to_bf16_rne(c1.w);
            }
        }
        #pragma unroll
        for (int mt = 0; mt < 4; ++mt)
            #pragma unroll
            for (int nt = 0; nt < 8; ++nt)
                acc[mt][nt] = __builtin_amdgcn_mfma_f32_16x16x32_bf16(
                    afrag[mt], bfrag[nt], acc[mt][nt], 0, 0, 0);
    }

    // Epilogue: C/D layout col = lane&15, row = quad*4 + reg.
    #pragma unroll
    for (int nt = 0; nt < 8; ++nt) {
        const int col = n_base + nt * 16 + lrow;
        const float bv = bias[col];
        #pragma unroll
        for (int mt = 0; mt < 4; ++mt) {
            float* op = out + (size_t)(m0 + mt * 16 + quad * 4) * D_MODEL + col;
            #pragma unroll
            for (int r = 0; r < 4; ++r)
                op[(size_t)r * D_MODEL] = acc[mt][nt][r] + bv;
        }
    }
}

extern "C" void kernel_launch(void* const* d_in, const int* in_sizes, int n_in,
                              void* d_out, int out_size, void* d_ws, size_t ws_size,
                              hipStream_t stream) {
    const float* chunk = (const float*)d_in[0];   // [262144, 512]
    const float* query = (const float*)d_in[1];   // [512]
    const float* w     = (const float*)d_in[2];   // [512, 512]
    const float* bias  = (const float*)d_in[3];   // [512]
    float* out = (float*)d_out;                   // [65536, 512]

    const size_t wb_bytes = (size_t)D_MODEL * D_MODEL * sizeof(unsigned short);
    if (ws_size >= wb_bytes && d_ws != nullptr) {
        unsigned short* wb = (unsigned short*)d_ws;
        convert_w_kernel<<<(D_MODEL * D_MODEL / 4) / 256, 256, 0, stream>>>(w, wb);
        attn_pool_gemm_kernel<true><<<GRID_BLOCKS, 256, 0, stream>>>(
            chunk, query, w, wb, bias, out);
    } else {
        attn_pool_gemm_kernel<false><<<GRID_BLOCKS, 256, 0, stream>>>(
            chunk, query, w, nullptr, bias, out);
    }
}